// Round 8
// baseline (178.381 us; speedup 1.0000x reference)
//
#include <hip/hip_runtime.h>
#include <math.h>

// Problem constants (match reference)
constexpr int T_LEN = 15360;
constexpr int B_DIM = 64;
constexpr int C_DIM = 64;
constexpr int NTHR  = 256;
constexpr int KHALF = 12;                 // k=25 taps -> halo 12
constexpr int SEG    = 12;                // segments per row
constexpr int CH     = T_LEN / SEG;       // 1280 elems / segment
constexpr int EPT    = CH / NTHR;         // 5 elems / thread (odd -> 2-way LDS alias, free)
constexpr int F4SEG  = CH / 4;            // 320 float4 / segment
constexpr int NROW   = B_DIM * C_DIM;     // 4096
constexpr int TSEG   = 4;                 // segments per A-block (20 KB contiguous)
constexpr int BPR    = SEG / TSEG;        // 3 A-blocks per row
constexpr int NABLK  = NROW * BPR;        // 12288
constexpr int CPT    = TSEG * F4SEG / NTHR;  // 5 float4 per thread in copy
constexpr int NBBLK  = 2048;              // B-kernel fixed grid (8/CU)

typedef float f32x4 __attribute__((ext_vector_type(4)));

struct BurstParams {
    float sf, endf, ef, inv_denom, head_end, tail_beg;
};

__device__ __forceinline__ BurstParams burst_params(const float* __restrict__ burst_u,
                                                    const float* __restrict__ start_u,
                                                    int b)
{
    const float bu   = burst_u[b];
    const float bfr  = 0.1f + bu * 0.4f;
    const int   blen = (int)floorf((float)T_LEN * bfr);
    int tmb = T_LEN - blen; if (tmb < 1) tmb = 1;
    const int   start = (int)floorf(start_u[b] * (float)tmb);
    const int   elen  = min(25, blen / 4);
    BurstParams p;
    p.sf   = (float)start;
    p.endf = p.sf + (float)blen;
    p.ef   = (float)elen;
    const float denom = fmaxf(p.ef - 1.0f, 1.0f);
    p.inv_denom = 1.0f / denom;
    p.head_end  = p.sf + p.ef;
    p.tail_beg  = p.endf - p.ef;
    return p;
}

// stage noise segment + halos into s_buf (interior at [KHALF, KHALF+CH))
__device__ __forceinline__ void stage_noise(const float* __restrict__ nrow, int g0,
                                            float* s_buf, int tid)
{
    const f32x4* nsrc = (const f32x4*)(nrow + g0);
    f32x4* sb4 = (f32x4*)(s_buf + KHALF);   // 48B offset -> 16B aligned
    #pragma unroll
    for (int it = 0; it < 2; ++it) {
        int q = tid + it * NTHR;
        if (q < F4SEG) sb4[q] = nsrc[q];
    }
    if (tid < KHALF) {
        int gl = g0 - KHALF + tid;
        s_buf[tid] = (gl >= 0) ? nrow[gl] : 0.f;
        int gr = g0 + CH + tid;
        s_buf[KHALF + CH + tid] = (gr < T_LEN) ? nrow[gr] : 0.f;
    }
}

// sliding 25-tap window over staged chunk; emits e[EPT] (emg_b values)
__device__ __forceinline__ void compute_emgb(const float* s_buf, int g0, int tid,
                                             const BurstParams& p, float* e)
{
    const float inv_k = 1.0f / 25.0f;
    const int l0 = KHALF + tid * EPT;
    float w = 0.f;
    #pragma unroll
    for (int d = -KHALF; d <= KHALF; ++d) w += s_buf[l0 + d];
    #pragma unroll
    for (int j = 0; j < EPT; ++j) {
        const float nv  = s_buf[l0 + j];
        const float emg = nv - w * inv_k;
        const float tt  = (float)(g0 + tid * EPT + j);
        const bool  inb = (tt >= p.sf) && (tt < p.endf);
        float ramped;
        if (tt < p.head_end)       ramped = (tt - p.sf) * p.inv_denom;
        else if (tt >= p.tail_beg) ramped = (p.endf - 1.0f - tt) * p.inv_denom;
        else                       ramped = 1.0f;
        const float m  = inb ? ((p.ef > 1.0f) ? ramped : 1.0f) : 0.0f;
        e[j] = emg * m;
        if (j < EPT - 1)
            w += s_buf[l0 + j + KHALF + 1] - s_buf[l0 + j - KHALF];
    }
}

// ====  Kernel A: contiguous bulk copy (unaffected) + stats + list push  ====
__global__ __launch_bounds__(NTHR, 8)
void emg_bulk_stats_kernel(const float* __restrict__ x,
                           const float* __restrict__ noise,
                           const float* __restrict__ apply_u,
                           const float* __restrict__ frac_u,
                           const float* __restrict__ ch_u,
                           const float* __restrict__ burst_u,
                           const float* __restrict__ start_u,
                           int*   __restrict__ count,      // [1], zeroed per call
                           int*   __restrict__ list,       // [NABLK]
                           float* __restrict__ partials,   // [NABLK][2]
                           float* __restrict__ out)
{
    const int idx = blockIdx.x;            // contiguous: block owns 20KB span
    const int row = idx / BPR;
    const int bir = idx - row * BPR;
    const int b   = row >> 6;
    const int c   = row & 63;
    const int tid = threadIdx.x;
    const int g0  = bir * TSEG * CH;

    __shared__ int   s_aff;
    __shared__ float s_red[8];
    __shared__ __align__(16) float s_buf[CH + 2 * KHALF + 1];

    // affected predicate via wave-0 ballot rank
    if (tid < 64) {
        const float myv = ch_u[(size_t)b * C_DIM + c];
        const float v   = ch_u[(size_t)b * C_DIM + tid];
        const bool pred = (v < myv) || (v == myv && tid < c);
        unsigned long long m = __ballot(pred);
        if (tid == 0) {
            int rank  = (int)__popcll(m);
            int n_aff = (int)floorf(((float)C_DIM * frac_u[b]) * 0.5f);
            if (n_aff < 1) n_aff = 1;
            int aff = (apply_u[b] <= 0.4f && rank < n_aff) ? 1 : 0;
            s_aff = aff;
            if (aff) {
                int slot = atomicAdd(count, 1);
                list[slot] = idx;
            }
        }
    }
    __syncthreads();

    const float* xrow = x   + (size_t)row * T_LEN;
    float*       orow = out + (size_t)row * T_LEN;

    if (!s_aff) {
        // streaming 20KB copy: plain cached float4; issue all loads, then stores
        const f32x4* xs = (const f32x4*)(xrow + g0);
        f32x4*       od = (f32x4*)(orow + g0);
        f32x4 v[CPT];
        #pragma unroll
        for (int it = 0; it < CPT; ++it) v[it] = xs[tid + it * NTHR];
        #pragma unroll
        for (int it = 0; it < CPT; ++it) od[tid + it * NTHR] = v[it];
        return;
    }

    // ---- affected: stats over 4 segments ----
    const BurstParams p = burst_params(burst_u, start_u, b);
    const float* nrow = noise + (size_t)row * T_LEN;

    float sumx2 = 0.f, sume2 = 0.f;
    for (int s = 0; s < TSEG; ++s) {
        const int sg0 = g0 + s * CH;
        const f32x4* x4 = (const f32x4*)(xrow + sg0);
        #pragma unroll
        for (int it = 0; it < 2; ++it) {
            int q = tid + it * NTHR;
            if (q < F4SEG) {
                f32x4 xv = x4[q];
                sumx2 += xv.x * xv.x + xv.y * xv.y + xv.z * xv.z + xv.w * xv.w;
            }
        }
        __syncthreads();   // prior seg's s_buf reads done
        stage_noise(nrow, sg0, s_buf, tid);
        __syncthreads();
        float e[EPT];
        compute_emgb(s_buf, sg0, tid, p, e);
        #pragma unroll
        for (int j = 0; j < EPT; ++j) sume2 += e[j] * e[j];
    }

    // block reduction
    float v1 = sumx2, v2 = sume2;
    #pragma unroll
    for (int off = 32; off > 0; off >>= 1) {
        v1 += __shfl_down(v1, off, 64);
        v2 += __shfl_down(v2, off, 64);
    }
    const int wave = tid >> 6;
    if ((tid & 63) == 0) { s_red[wave] = v1; s_red[wave + 4] = v2; }
    __syncthreads();
    if (tid == 0) {
        partials[(size_t)idx * 2]     = s_red[0] + s_red[1] + s_red[2] + s_red[3];
        partials[(size_t)idx * 2 + 1] = s_red[4] + s_red[5] + s_red[6] + s_red[7];
    }
}

// ====  Kernel B: apply over compacted affected list only  ====
__global__ __launch_bounds__(NTHR, 8)
void emg_apply_kernel(const float* __restrict__ x,
                      const float* __restrict__ noise,
                      const float* __restrict__ burst_u,
                      const float* __restrict__ start_u,
                      const float* __restrict__ snr_u,
                      const int*   __restrict__ count,
                      const int*   __restrict__ list,
                      const float* __restrict__ partials,
                      float* __restrict__ out)
{
    const int tid = threadIdx.x;
    __shared__ __align__(16) float s_buf[CH + 2 * KHALF + 1];

    const int n = count[0];
    for (int e = blockIdx.x; e < n; e += NBBLK) {
        const int idx = list[e];
        const int row = idx / BPR;
        const int bir = idx - row * BPR;
        const int b   = row >> 6;
        const int g0  = bir * TSEG * CH;

        // row sums from the 3 per-block partials (L2-hot)
        const float* pr = partials + (size_t)row * BPR * 2;
        const float sx = pr[0] + pr[2] + pr[4];
        const float se = pr[1] + pr[3] + pr[5];
        const float sig_p = sqrtf(sx / (float)T_LEN) + 1e-8f;
        const float noi_p = sqrtf(se / (float)T_LEN) + 1e-8f;
        const float snr   = 0.5f + snr_u[b] * 2.5f;
        const float coef  = sig_p / (noi_p * snr);

        const BurstParams p = burst_params(burst_u, start_u, b);
        const float* xrow = x     + (size_t)row * T_LEN;
        const float* nrow = noise + (size_t)row * T_LEN;
        float*       orow = out   + (size_t)row * T_LEN;

        for (int s = 0; s < TSEG; ++s) {
            const int sg0 = g0 + s * CH;
            __syncthreads();   // prior seg/entry s_buf reads done
            stage_noise(nrow, sg0, s_buf, tid);
            __syncthreads();

            float ev[EPT];
            compute_emgb(s_buf, sg0, tid, p, ev);
            __syncthreads();   // window reads done -> safe to overwrite interior

            const int l0 = KHALF + tid * EPT;
            #pragma unroll
            for (int j = 0; j < EPT; ++j) s_buf[l0 + j] = ev[j];
            __syncthreads();

            // coalesced float4 output: out = x + coef * emg_b
            const f32x4* sb4  = (const f32x4*)(s_buf + KHALF);
            const f32x4* xsrc = (const f32x4*)(xrow + sg0);
            f32x4*       odst = (f32x4*)(orow + sg0);
            #pragma unroll
            for (int it = 0; it < 2; ++it) {
                int q = tid + it * NTHR;
                if (q < F4SEG) {
                    f32x4 evv = sb4[q];
                    f32x4 xv  = xsrc[q];
                    f32x4 ov;
                    ov.x = xv.x + coef * evv.x;
                    ov.y = xv.y + coef * evv.y;
                    ov.z = xv.z + coef * evv.z;
                    ov.w = xv.w + coef * evv.w;
                    odst[q] = ov;
                }
            }
        }
    }
}

extern "C" void kernel_launch(void* const* d_in, const int* in_sizes, int n_in,
                              void* d_out, int out_size, void* d_ws, size_t ws_size,
                              hipStream_t stream) {
    const float* x       = (const float*)d_in[0];
    const float* noise   = (const float*)d_in[1];
    const float* apply_u = (const float*)d_in[2];
    const float* frac_u  = (const float*)d_in[3];
    const float* ch_u    = (const float*)d_in[4];
    const float* burst_u = (const float*)d_in[5];
    const float* start_u = (const float*)d_in[6];
    const float* snr_u   = (const float*)d_in[7];
    float* out = (float*)d_out;

    // ws layout: [0,256) count; [256, 256+NABLK*8) partials; then list
    int*   count    = (int*)d_ws;
    float* partials = (float*)((char*)d_ws + 256);
    int*   list     = (int*)((char*)d_ws + 256 + NABLK * 2 * sizeof(float));

    hipMemsetAsync(count, 0, sizeof(int), stream);

    emg_bulk_stats_kernel<<<dim3(NABLK), dim3(NTHR), 0, stream>>>(
        x, noise, apply_u, frac_u, ch_u, burst_u, start_u,
        count, list, partials, out);
    emg_apply_kernel<<<dim3(NBBLK), dim3(NTHR), 0, stream>>>(
        x, noise, burst_u, start_u, snr_u, count, list, partials, out);
}

// Round 9
// 153.668 us; speedup vs baseline: 1.1608x; 1.1608x over previous
//
#include <hip/hip_runtime.h>
#include <math.h>

// Problem constants (match reference)
constexpr int T_LEN = 15360;
constexpr int B_DIM = 64;
constexpr int C_DIM = 64;
constexpr int NTHR  = 256;
constexpr int KHALF = 12;                 // k=25 taps -> halo 12
constexpr int SEG   = 12;                 // 1280-elem segments per row
constexpr int CH    = T_LEN / SEG;        // 1280
constexpr int EPT   = CH / NTHR;          // 5 elems/thread (odd -> benign LDS alias)
constexpr int F4SEG = CH / 4;             // 320 float4 / segment
constexpr int NROW  = B_DIM * C_DIM;      // 4096
constexpr int TSEG  = 4;                  // segments per K3 tile
constexpr int TILE_ELEMS = TSEG * CH;     // 5120 (20 KB)
constexpr int TPR   = SEG / TSEG;         // 3 tiles per row
constexpr int NTILE = NROW * TPR;         // 12288
constexpr int CPT   = TILE_ELEMS / 4 / NTHR;  // 5 float4 per thread (copy)
constexpr int NBLK2 = 1024;               // stats grid
constexpr int NBLK3 = 2048;               // final grid (1 resident set, 6 iters)

typedef float f32x4 __attribute__((ext_vector_type(4)));

struct BurstParams {
    float sf, endf, ef, inv_denom, head_end, tail_beg;
};

__device__ __forceinline__ BurstParams burst_params(const float* __restrict__ burst_u,
                                                    const float* __restrict__ start_u,
                                                    int b)
{
    const float bu   = burst_u[b];
    const float bfr  = 0.1f + bu * 0.4f;
    const int   blen = (int)floorf((float)T_LEN * bfr);
    int tmb = T_LEN - blen; if (tmb < 1) tmb = 1;
    const int   start = (int)floorf(start_u[b] * (float)tmb);
    const int   elen  = min(25, blen / 4);
    BurstParams p;
    p.sf   = (float)start;
    p.endf = p.sf + (float)blen;
    p.ef   = (float)elen;
    const float denom = fmaxf(p.ef - 1.0f, 1.0f);
    p.inv_denom = 1.0f / denom;
    p.head_end  = p.sf + p.ef;
    p.tail_beg  = p.endf - p.ef;
    return p;
}

// stage noise segment + halos into s_buf (interior at [KHALF, KHALF+CH))
__device__ __forceinline__ void stage_noise(const float* __restrict__ nrow, int g0,
                                            float* s_buf, int tid)
{
    const f32x4* nsrc = (const f32x4*)(nrow + g0);
    f32x4* sb4 = (f32x4*)(s_buf + KHALF);   // 48B offset -> 16B aligned
    #pragma unroll
    for (int it = 0; it < 2; ++it) {
        int q = tid + it * NTHR;
        if (q < F4SEG) sb4[q] = nsrc[q];
    }
    if (tid < KHALF) {
        int gl = g0 - KHALF + tid;
        s_buf[tid] = (gl >= 0) ? nrow[gl] : 0.f;
        int gr = g0 + CH + tid;
        s_buf[KHALF + CH + tid] = (gr < T_LEN) ? nrow[gr] : 0.f;
    }
}

// sliding 25-tap window over staged chunk; emits e[EPT] (emg_b values)
__device__ __forceinline__ void compute_emgb(const float* s_buf, int g0, int tid,
                                             const BurstParams& p, float* e)
{
    const float inv_k = 1.0f / 25.0f;
    const int l0 = KHALF + tid * EPT;
    float w = 0.f;
    #pragma unroll
    for (int d = -KHALF; d <= KHALF; ++d) w += s_buf[l0 + d];
    #pragma unroll
    for (int j = 0; j < EPT; ++j) {
        const float nv  = s_buf[l0 + j];
        const float emg = nv - w * inv_k;
        const float tt  = (float)(g0 + tid * EPT + j);
        const bool  inb = (tt >= p.sf) && (tt < p.endf);
        float ramped;
        if (tt < p.head_end)       ramped = (tt - p.sf) * p.inv_denom;
        else if (tt >= p.tail_beg) ramped = (p.endf - 1.0f - tt) * p.inv_denom;
        else                       ramped = 1.0f;
        const float m  = inb ? ((p.ef > 1.0f) ? ramped : 1.0f) : 0.0f;
        e[j] = emg * m;
        if (j < EPT - 1)
            w += s_buf[l0 + j + KHALF + 1] - s_buf[l0 + j - KHALF];
    }
}

// ==== K1: per-row affected flags + compacted row list ====
__global__ __launch_bounds__(64)
void emg_flags_kernel(const float* __restrict__ apply_u,
                      const float* __restrict__ frac_u,
                      const float* __restrict__ ch_u,
                      int* __restrict__ flags,
                      int* __restrict__ rowlist,
                      int* __restrict__ count)
{
    const int b = blockIdx.x;
    const int c = threadIdx.x;
    __shared__ float s_ch[C_DIM];
    s_ch[c] = ch_u[(size_t)b * C_DIM + c];
    __syncthreads();
    const float myv = s_ch[c];
    int rank = 0;
    #pragma unroll 8
    for (int i = 0; i < C_DIM; ++i) {
        float v = s_ch[i];
        rank += (v < myv || (v == myv && i < c)) ? 1 : 0;
    }
    int n_aff = (int)floorf(((float)C_DIM * frac_u[b]) * 0.5f);
    if (n_aff < 1) n_aff = 1;
    const int aff = (apply_u[b] <= 0.4f && rank < n_aff) ? 1 : 0;
    const int row = b * C_DIM + c;
    flags[row] = aff;
    if (aff) {
        int slot = atomicAdd(count, 1);
        rowlist[slot] = row;
    }
}

// ==== K2: per-segment stats over affected rows only ====
__global__ __launch_bounds__(NTHR, 8)
void emg_stats_kernel(const float* __restrict__ x,
                      const float* __restrict__ noise,
                      const float* __restrict__ burst_u,
                      const float* __restrict__ start_u,
                      const int* __restrict__ count,
                      const int* __restrict__ rowlist,
                      float* __restrict__ partials)
{
    const int tid = threadIdx.x;
    __shared__ float s_red[8];
    __shared__ __align__(16) float s_buf[CH + 2 * KHALF + 1];

    const int ntile = count[0] * SEG;
    for (int e = blockIdx.x; e < ntile; e += NBLK2) {
        const int r   = e / SEG;
        const int seg = e - r * SEG;
        const int row = rowlist[r];
        const int b   = row >> 6;
        const int g0  = seg * CH;
        const BurstParams p = burst_params(burst_u, start_u, b);
        const float* xrow = x     + (size_t)row * T_LEN;
        const float* nrow = noise + (size_t)row * T_LEN;

        float sumx2 = 0.f;
        const f32x4* x4 = (const f32x4*)(xrow + g0);
        #pragma unroll
        for (int it = 0; it < 2; ++it) {
            int q = tid + it * NTHR;
            if (q < F4SEG) {
                f32x4 xv = x4[q];
                sumx2 += xv.x * xv.x + xv.y * xv.y + xv.z * xv.z + xv.w * xv.w;
            }
        }

        __syncthreads();   // protect s_buf/s_red reuse across iterations
        stage_noise(nrow, g0, s_buf, tid);
        __syncthreads();

        float ev[EPT];
        compute_emgb(s_buf, g0, tid, p, ev);
        float sume2 = 0.f;
        #pragma unroll
        for (int j = 0; j < EPT; ++j) sume2 += ev[j] * ev[j];

        float v1 = sumx2, v2 = sume2;
        #pragma unroll
        for (int off = 32; off > 0; off >>= 1) {
            v1 += __shfl_down(v1, off, 64);
            v2 += __shfl_down(v2, off, 64);
        }
        const int wave = tid >> 6;
        if ((tid & 63) == 0) { s_red[wave] = v1; s_red[wave + 4] = v2; }
        __syncthreads();
        if (tid == 0) {
            partials[((size_t)row * SEG + seg) * 2]     = s_red[0] + s_red[1] + s_red[2] + s_red[3];
            partials[((size_t)row * SEG + seg) * 2 + 1] = s_red[4] + s_red[5] + s_red[6] + s_red[7];
        }
    }
}

// ==== K2b: fold partials -> per-row coef ====
__global__ __launch_bounds__(NTHR)
void emg_coef_kernel(const float* __restrict__ snr_u,
                     const int* __restrict__ count,
                     const int* __restrict__ rowlist,
                     const float* __restrict__ partials,
                     float* __restrict__ coef)
{
    const int n = count[0];
    for (int t = blockIdx.x * NTHR + threadIdx.x; t < n; t += gridDim.x * NTHR) {
        const int row = rowlist[t];
        const float* pr = partials + (size_t)row * SEG * 2;
        float sx = 0.f, se = 0.f;
        #pragma unroll
        for (int s = 0; s < SEG; ++s) { sx += pr[2 * s]; se += pr[2 * s + 1]; }
        const float sig_p = sqrtf(sx / (float)T_LEN) + 1e-8f;
        const float noi_p = sqrtf(se / (float)T_LEN) + 1e-8f;
        const float snr   = 0.5f + snr_u[row >> 6] * 2.5f;
        coef[row] = sig_p / (noi_p * snr);
    }
}

// ==== K3: grid-stride copy (unaffected) / apply (affected) ====
__global__ __launch_bounds__(NTHR, 8)
void emg_final_kernel(const float* __restrict__ x,
                      const float* __restrict__ noise,
                      const float* __restrict__ burst_u,
                      const float* __restrict__ start_u,
                      const int*   __restrict__ flags,
                      const float* __restrict__ coef,
                      float* __restrict__ out)
{
    const int tid = threadIdx.x;
    __shared__ __align__(16) float s_buf[CH + 2 * KHALF + 1];

    for (int idx = blockIdx.x; idx < NTILE; idx += NBLK3) {
        const int row = idx / TPR;
        const size_t base = (size_t)idx * TILE_ELEMS;   // tiles never cross rows
        const f32x4* xs = (const f32x4*)(x + base);
        f32x4*       od = (f32x4*)(out + base);

        if (!flags[row]) {
            // pure streaming copy, no barriers -> iterations pipeline
            f32x4 v[CPT];
            #pragma unroll
            for (int it = 0; it < CPT; ++it) v[it] = xs[tid + it * NTHR];
            #pragma unroll
            for (int it = 0; it < CPT; ++it) od[tid + it * NTHR] = v[it];
            continue;
        }

        // affected tile: 4 staged segments, out = x + coef * emg_b
        const int b   = row >> 6;
        const int tir = idx - row * TPR;
        const int g0  = tir * TILE_ELEMS;
        const float cf = coef[row];
        const BurstParams p = burst_params(burst_u, start_u, b);
        const float* xrow = x     + (size_t)row * T_LEN;
        const float* nrow = noise + (size_t)row * T_LEN;
        float*       orow = out   + (size_t)row * T_LEN;

        for (int s = 0; s < TSEG; ++s) {
            const int sg0 = g0 + s * CH;
            __syncthreads();   // prior s_buf reads done
            stage_noise(nrow, sg0, s_buf, tid);
            __syncthreads();

            float ev[EPT];
            compute_emgb(s_buf, sg0, tid, p, ev);
            __syncthreads();   // window reads done -> safe to overwrite

            const int l0 = KHALF + tid * EPT;
            #pragma unroll
            for (int j = 0; j < EPT; ++j) s_buf[l0 + j] = ev[j];
            __syncthreads();

            const f32x4* sb4  = (const f32x4*)(s_buf + KHALF);
            const f32x4* xsrc = (const f32x4*)(xrow + sg0);
            f32x4*       odst = (f32x4*)(orow + sg0);
            #pragma unroll
            for (int it = 0; it < 2; ++it) {
                int q = tid + it * NTHR;
                if (q < F4SEG) {
                    f32x4 evv = sb4[q];
                    f32x4 xv  = xsrc[q];
                    f32x4 ov;
                    ov.x = xv.x + cf * evv.x;
                    ov.y = xv.y + cf * evv.y;
                    ov.z = xv.z + cf * evv.z;
                    ov.w = xv.w + cf * evv.w;
                    odst[q] = ov;
                }
            }
        }
    }
}

extern "C" void kernel_launch(void* const* d_in, const int* in_sizes, int n_in,
                              void* d_out, int out_size, void* d_ws, size_t ws_size,
                              hipStream_t stream) {
    const float* x       = (const float*)d_in[0];
    const float* noise   = (const float*)d_in[1];
    const float* apply_u = (const float*)d_in[2];
    const float* frac_u  = (const float*)d_in[3];
    const float* ch_u    = (const float*)d_in[4];
    const float* burst_u = (const float*)d_in[5];
    const float* start_u = (const float*)d_in[6];
    const float* snr_u   = (const float*)d_in[7];
    float* out = (float*)d_out;

    // ws layout: count | rowlist[4096] | flags[4096] | partials[4096*12*2] | coef[4096]
    char* w = (char*)d_ws;
    int*   count    = (int*)w;                               // 256 B slot
    int*   rowlist  = (int*)(w + 256);                       // 16 KB
    int*   flags    = (int*)(w + 256 + 16 * 1024);           // 16 KB
    float* partials = (float*)(w + 256 + 32 * 1024);         // 384 KB
    float* coef     = (float*)(w + 256 + 32 * 1024 + NROW * SEG * 2 * sizeof(float));

    hipMemsetAsync(count, 0, sizeof(int), stream);

    emg_flags_kernel<<<dim3(B_DIM), dim3(64), 0, stream>>>(
        apply_u, frac_u, ch_u, flags, rowlist, count);
    emg_stats_kernel<<<dim3(NBLK2), dim3(NTHR), 0, stream>>>(
        x, noise, burst_u, start_u, count, rowlist, partials);
    emg_coef_kernel<<<dim3(16), dim3(NTHR), 0, stream>>>(
        snr_u, count, rowlist, partials, coef);
    emg_final_kernel<<<dim3(NBLK3), dim3(NTHR), 0, stream>>>(
        x, noise, burst_u, start_u, flags, coef, out);
}

// Round 10
// 139.086 us; speedup vs baseline: 1.2825x; 1.1048x over previous
//
#include <hip/hip_runtime.h>
#include <math.h>

// Problem constants (match reference)
constexpr int T_LEN = 15360;
constexpr int B_DIM = 64;
constexpr int C_DIM = 64;
constexpr int NTHR  = 256;
constexpr int KHALF = 12;                 // k=25 taps -> halo 12
constexpr int SEG   = 12;                 // 1280-elem segments per row
constexpr int CH    = T_LEN / SEG;        // 1280
constexpr int EPT   = CH / NTHR;          // 5 elems/thread (odd -> benign LDS alias)
constexpr int F4SEG = CH / 4;             // 320 float4 / segment
constexpr int NROW  = B_DIM * C_DIM;      // 4096
constexpr int NBLK2 = 1024;               // stats grid

typedef float f32x4 __attribute__((ext_vector_type(4)));

struct BurstParams {
    float sf, endf, ef, inv_denom, head_end, tail_beg;
};

__device__ __forceinline__ BurstParams burst_params(const float* __restrict__ burst_u,
                                                    const float* __restrict__ start_u,
                                                    int b)
{
    const float bu   = burst_u[b];
    const float bfr  = 0.1f + bu * 0.4f;
    const int   blen = (int)floorf((float)T_LEN * bfr);
    int tmb = T_LEN - blen; if (tmb < 1) tmb = 1;
    const int   start = (int)floorf(start_u[b] * (float)tmb);
    const int   elen  = min(25, blen / 4);
    BurstParams p;
    p.sf   = (float)start;
    p.endf = p.sf + (float)blen;
    p.ef   = (float)elen;
    const float denom = fmaxf(p.ef - 1.0f, 1.0f);
    p.inv_denom = 1.0f / denom;
    p.head_end  = p.sf + p.ef;
    p.tail_beg  = p.endf - p.ef;
    return p;
}

// stage noise segment + halos into s_buf (interior at [KHALF, KHALF+CH))
__device__ __forceinline__ void stage_noise(const float* __restrict__ nrow, int g0,
                                            float* s_buf, int tid)
{
    const f32x4* nsrc = (const f32x4*)(nrow + g0);
    f32x4* sb4 = (f32x4*)(s_buf + KHALF);   // 48B offset -> 16B aligned
    #pragma unroll
    for (int it = 0; it < 2; ++it) {
        int q = tid + it * NTHR;
        if (q < F4SEG) sb4[q] = nsrc[q];
    }
    if (tid < KHALF) {
        int gl = g0 - KHALF + tid;
        s_buf[tid] = (gl >= 0) ? nrow[gl] : 0.f;
        int gr = g0 + CH + tid;
        s_buf[KHALF + CH + tid] = (gr < T_LEN) ? nrow[gr] : 0.f;
    }
}

// sliding 25-tap window over staged chunk; emits e[EPT] (emg_b values)
__device__ __forceinline__ void compute_emgb(const float* s_buf, int g0, int tid,
                                             const BurstParams& p, float* e)
{
    const float inv_k = 1.0f / 25.0f;
    const int l0 = KHALF + tid * EPT;
    float w = 0.f;
    #pragma unroll
    for (int d = -KHALF; d <= KHALF; ++d) w += s_buf[l0 + d];
    #pragma unroll
    for (int j = 0; j < EPT; ++j) {
        const float nv  = s_buf[l0 + j];
        const float emg = nv - w * inv_k;
        const float tt  = (float)(g0 + tid * EPT + j);
        const bool  inb = (tt >= p.sf) && (tt < p.endf);
        float ramped;
        if (tt < p.head_end)       ramped = (tt - p.sf) * p.inv_denom;
        else if (tt >= p.tail_beg) ramped = (p.endf - 1.0f - tt) * p.inv_denom;
        else                       ramped = 1.0f;
        const float m  = inb ? ((p.ef > 1.0f) ? ramped : 1.0f) : 0.0f;
        e[j] = emg * m;
        if (j < EPT - 1)
            w += s_buf[l0 + j + KHALF + 1] - s_buf[l0 + j - KHALF];
    }
}

// ==== K1: per-row affected flags + compacted row list ====
__global__ __launch_bounds__(64)
void emg_flags_kernel(const float* __restrict__ apply_u,
                      const float* __restrict__ frac_u,
                      const float* __restrict__ ch_u,
                      int* __restrict__ flags,
                      int* __restrict__ rowlist,
                      int* __restrict__ count)
{
    const int b = blockIdx.x;
    const int c = threadIdx.x;
    __shared__ float s_ch[C_DIM];
    s_ch[c] = ch_u[(size_t)b * C_DIM + c];
    __syncthreads();
    const float myv = s_ch[c];
    int rank = 0;
    #pragma unroll 8
    for (int i = 0; i < C_DIM; ++i) {
        float v = s_ch[i];
        rank += (v < myv || (v == myv && i < c)) ? 1 : 0;
    }
    int n_aff = (int)floorf(((float)C_DIM * frac_u[b]) * 0.5f);
    if (n_aff < 1) n_aff = 1;
    const int aff = (apply_u[b] <= 0.4f && rank < n_aff) ? 1 : 0;
    const int row = b * C_DIM + c;
    flags[row] = aff;
    if (aff) {
        int slot = atomicAdd(count, 1);
        rowlist[slot] = row;
    }
}

// ==== K2: per-segment stats over affected rows only ====
__global__ __launch_bounds__(NTHR, 8)
void emg_stats_kernel(const float* __restrict__ x,
                      const float* __restrict__ noise,
                      const float* __restrict__ burst_u,
                      const float* __restrict__ start_u,
                      const int* __restrict__ count,
                      const int* __restrict__ rowlist,
                      float* __restrict__ partials)
{
    const int tid = threadIdx.x;
    __shared__ float s_red[8];
    __shared__ __align__(16) float s_buf[CH + 2 * KHALF + 1];

    const int ntile = count[0] * SEG;
    for (int e = blockIdx.x; e < ntile; e += NBLK2) {
        const int r   = e / SEG;
        const int seg = e - r * SEG;
        const int row = rowlist[r];
        const int b   = row >> 6;
        const int g0  = seg * CH;
        const BurstParams p = burst_params(burst_u, start_u, b);
        const float* xrow = x     + (size_t)row * T_LEN;
        const float* nrow = noise + (size_t)row * T_LEN;

        float sumx2 = 0.f;
        const f32x4* x4 = (const f32x4*)(xrow + g0);
        #pragma unroll
        for (int it = 0; it < 2; ++it) {
            int q = tid + it * NTHR;
            if (q < F4SEG) {
                f32x4 xv = x4[q];
                sumx2 += xv.x * xv.x + xv.y * xv.y + xv.z * xv.z + xv.w * xv.w;
            }
        }

        __syncthreads();   // protect s_buf/s_red reuse across iterations
        stage_noise(nrow, g0, s_buf, tid);
        __syncthreads();

        float ev[EPT];
        compute_emgb(s_buf, g0, tid, p, ev);
        float sume2 = 0.f;
        #pragma unroll
        for (int j = 0; j < EPT; ++j) sume2 += ev[j] * ev[j];

        float v1 = sumx2, v2 = sume2;
        #pragma unroll
        for (int off = 32; off > 0; off >>= 1) {
            v1 += __shfl_down(v1, off, 64);
            v2 += __shfl_down(v2, off, 64);
        }
        const int wave = tid >> 6;
        if ((tid & 63) == 0) { s_red[wave] = v1; s_red[wave + 4] = v2; }
        __syncthreads();
        if (tid == 0) {
            partials[((size_t)row * SEG + seg) * 2]     = s_red[0] + s_red[1] + s_red[2] + s_red[3];
            partials[((size_t)row * SEG + seg) * 2 + 1] = s_red[4] + s_red[5] + s_red[6] + s_red[7];
        }
    }
}

// ==== K2b: fold partials -> per-row coef ====
__global__ __launch_bounds__(NTHR)
void emg_coef_kernel(const float* __restrict__ snr_u,
                     const int* __restrict__ count,
                     const int* __restrict__ rowlist,
                     const float* __restrict__ partials,
                     float* __restrict__ coef)
{
    const int n = count[0];
    for (int t = blockIdx.x * NTHR + threadIdx.x; t < n; t += gridDim.x * NTHR) {
        const int row = rowlist[t];
        const float* pr = partials + (size_t)row * SEG * 2;
        float sx = 0.f, se = 0.f;
        #pragma unroll
        for (int s = 0; s < SEG; ++s) { sx += pr[2 * s]; se += pr[2 * s + 1]; }
        const float sig_p = sqrtf(sx / (float)T_LEN) + 1e-8f;
        const float noi_p = sqrtf(se / (float)T_LEN) + 1e-8f;
        const float snr   = 0.5f + snr_u[row >> 6] * 2.5f;
        coef[row] = sig_p / (noi_p * snr);
    }
}

// ==== K3: fused x-major pass — copy (unaffected) / apply (affected) ====
// grid (NROW, SEG): blockIdx.x = row (fast), blockIdx.y = seg.
// Consecutive blocks stream the same segment across consecutive rows —
// the marching-window pattern measured at ~4.7 TB/s in R4.
__global__ __launch_bounds__(NTHR, 8)
void emg_fused_kernel(const float* __restrict__ x,
                      const float* __restrict__ noise,
                      const float* __restrict__ burst_u,
                      const float* __restrict__ start_u,
                      const int*   __restrict__ flags,
                      const float* __restrict__ coef,
                      float* __restrict__ out)
{
    const int row = blockIdx.x;
    const int seg = blockIdx.y;
    const int tid = threadIdx.x;
    const int g0  = seg * CH;

    __shared__ __align__(16) float s_buf[CH + 2 * KHALF + 1];

    const float* xrow = x   + (size_t)row * T_LEN;
    float*       orow = out + (size_t)row * T_LEN;
    const f32x4* x4   = (const f32x4*)(xrow + g0);
    f32x4*       o4   = (f32x4*)(orow + g0);

    if (!flags[row]) {
        // barrier-free 5KB copy
        #pragma unroll
        for (int it = 0; it < 2; ++it) {
            int q = tid + it * NTHR;
            if (q < F4SEG) o4[q] = x4[q];
        }
        return;
    }

    // affected: coef known — apply directly
    const int b = row >> 6;
    const float cf = coef[row];
    const BurstParams p = burst_params(burst_u, start_u, b);
    const float* nrow = noise + (size_t)row * T_LEN;

    stage_noise(nrow, g0, s_buf, tid);
    __syncthreads();

    float ev[EPT];
    compute_emgb(s_buf, g0, tid, p, ev);
    __syncthreads();   // window reads done -> safe to overwrite interior

    const int l0 = KHALF + tid * EPT;
    #pragma unroll
    for (int j = 0; j < EPT; ++j) s_buf[l0 + j] = ev[j];
    __syncthreads();

    const f32x4* sb4 = (const f32x4*)(s_buf + KHALF);
    #pragma unroll
    for (int it = 0; it < 2; ++it) {
        int q = tid + it * NTHR;
        if (q < F4SEG) {
            f32x4 evv = sb4[q];
            f32x4 xv  = x4[q];
            f32x4 ov;
            ov.x = xv.x + cf * evv.x;
            ov.y = xv.y + cf * evv.y;
            ov.z = xv.z + cf * evv.z;
            ov.w = xv.w + cf * evv.w;
            o4[q] = ov;
        }
    }
}

extern "C" void kernel_launch(void* const* d_in, const int* in_sizes, int n_in,
                              void* d_out, int out_size, void* d_ws, size_t ws_size,
                              hipStream_t stream) {
    const float* x       = (const float*)d_in[0];
    const float* noise   = (const float*)d_in[1];
    const float* apply_u = (const float*)d_in[2];
    const float* frac_u  = (const float*)d_in[3];
    const float* ch_u    = (const float*)d_in[4];
    const float* burst_u = (const float*)d_in[5];
    const float* start_u = (const float*)d_in[6];
    const float* snr_u   = (const float*)d_in[7];
    float* out = (float*)d_out;

    // ws layout: count | rowlist[4096] | flags[4096] | partials[4096*12*2] | coef[4096]
    char* w = (char*)d_ws;
    int*   count    = (int*)w;                               // 256 B slot
    int*   rowlist  = (int*)(w + 256);                       // 16 KB
    int*   flags    = (int*)(w + 256 + 16 * 1024);           // 16 KB
    float* partials = (float*)(w + 256 + 32 * 1024);         // 384 KB
    float* coef     = (float*)(w + 256 + 32 * 1024 + NROW * SEG * 2 * sizeof(float));

    hipMemsetAsync(count, 0, sizeof(int), stream);

    emg_flags_kernel<<<dim3(B_DIM), dim3(64), 0, stream>>>(
        apply_u, frac_u, ch_u, flags, rowlist, count);
    emg_stats_kernel<<<dim3(NBLK2), dim3(NTHR), 0, stream>>>(
        x, noise, burst_u, start_u, count, rowlist, partials);
    emg_coef_kernel<<<dim3(16), dim3(NTHR), 0, stream>>>(
        snr_u, count, rowlist, partials, coef);
    emg_fused_kernel<<<dim3(NROW, SEG), dim3(NTHR), 0, stream>>>(
        x, noise, burst_u, start_u, flags, coef, out);
}